// Round 8
// baseline (506.613 us; speedup 1.0000x reference)
//
#include <hip/hip_runtime.h>
#include <math.h>

#define HWP 16384   // pixels per image (128*128)
#define CIN 192
#define C3  576
#define CH  48      // c_head
#define NHD 4       // heads
#define NS  64      // s-partitions for QK^T partial reduction (256 s each)
#define PBF 3145728 // per-batch elems of one [192,16384] matrix (= 16384*192)
#define QKPAD 68    // LDS row stride for qk_partial fp32 tiles
#define KG  192     // GEMM K (both GEMMs)

typedef unsigned short u16;
typedef __attribute__((ext_vector_type(8))) short bf16x8;
typedef __attribute__((ext_vector_type(4))) float f32x4;

__device__ __forceinline__ u16 f2bf(float f) {
  unsigned int u = __builtin_bit_cast(unsigned int, f);
  u = (u + 0x7FFFu + ((u >> 16) & 1u)) >> 16;
  return (u16)u;
}
__device__ __forceinline__ float bflo(unsigned int u) {
  return __builtin_bit_cast(float, u << 16);
}
__device__ __forceinline__ float bfhi(unsigned int u) {
  return __builtin_bit_cast(float, u & 0xFFFF0000u);
}
__device__ __forceinline__ unsigned pk2(float a, float b) {
  return (unsigned)f2bf(a) | ((unsigned)f2bf(b) << 16);
}

// ---------------- convert + transpose weights -> bf16 [N][K] ----------------
__global__ __launch_bounds__(256) void convert_w_k(
    const float* __restrict__ qkvW, const float* __restrict__ projW,
    u16* __restrict__ qkvWT, u16* __restrict__ projWT) {
  int idx = blockIdx.x * 256 + threadIdx.x;
  if (idx < C3 * CIN) {
    int n = idx / CIN, k = idx % CIN;
    qkvWT[idx] = f2bf(qkvW[(size_t)k * C3 + n]);
  } else {
    int i2 = idx - C3 * CIN;
    if (i2 < CIN * CIN) {
      int n = i2 / CIN, k = i2 % CIN;
      projWT[i2] = f2bf(projW[(size_t)k * CIN + n]);
    }
  }
}

// ---------------- tall-skinny bf16 MFMA GEMM, K=192 ----------------
// C[M,N] = A[M,K] * BT[N,K]^T. BM=128, BN=64; 256 thr (4 waves, wave=64x32).
// B panel (64x192, 24KB, XOR-swizzled) staged ONCE; A fragments loaded
// directly from global (L1/L2-served; XCD swizzle gives A-tile reuse) ->
// no barriers in the K loop. A_F32: convert fp32->bf16 in-register.
template <bool A_F32, bool C_BF16>
__global__ __launch_bounds__(256) void gemm_skinny(
    const void* __restrict__ Ab, const u16* __restrict__ BTb, void* __restrict__ Cv,
    int N, long strideA, long strideBT, long strideC) {
  __shared__ __align__(16) u16 Bs[64 * KG];
  const int t = threadIdx.x;
  const int lane = t & 63, wave = t >> 6;
  const int z = blockIdx.z;
  const int esz = A_F32 ? 4 : 2;
  const char* A = (const char*)Ab + (size_t)z * strideA * esz;
  const u16* BT = BTb + (size_t)z * strideBT;

  const int nT = N >> 6;
  const int nwg = gridDim.x;
  const int bid = blockIdx.x;
  const int q = nwg >> 3, r = nwg & 7;
  const int xcd = bid & 7, idx = bid >> 3;
  const int swz = (xcd < r) ? (xcd * (q + 1) + idx)
                            : (r * (q + 1) + (xcd - r) * q + idx);
  const int m0 = (swz / nT) * 128, n0 = (swz % nT) * 64;
  const int wm = (wave >> 1) * 64, wn = (wave & 1) * 32;

  // stage B: 64 rows x 192 k bf16 = 1536 x 16B slots, 6 per thread; swizzled
#pragma unroll
  for (int i = 0; i < 6; ++i) {
    int slot = t + i * 256;
    int row = slot / 24, c = slot % 24;
    uint4 v = *(const uint4*)&BT[(size_t)(n0 + row) * KG + c * 8];
    *(uint4*)((char*)Bs + row * 384 + ((c * 16) ^ ((row & 7) << 4))) = v;
  }
  __syncthreads();

  f32x4 acc[4][2];
#pragma unroll
  for (int mi = 0; mi < 4; ++mi)
#pragma unroll
    for (int ni = 0; ni < 2; ++ni) acc[mi][ni] = (f32x4){0.f, 0.f, 0.f, 0.f};

  const int lrow = lane & 15;
  const int lko = (lane >> 4) * 8;   // elem offset within 32-k slice
  const char* arow[4];
#pragma unroll
  for (int mi = 0; mi < 4; ++mi)
    arow[mi] = A + ((size_t)(m0 + wm + mi * 16 + lrow) * KG + lko) * esz;

#pragma unroll
  for (int kk = 0; kk < 6; ++kk) {
    bf16x8 a[4], b[2];
#pragma unroll
    for (int mi = 0; mi < 4; ++mi) {
      if (A_F32) {
        const float* p = (const float*)(arow[mi] + kk * 32 * 4);
        float4 f0 = *(const float4*)p;
        float4 f1 = *(const float4*)(p + 4);
        uint4 u;
        u.x = pk2(f0.x, f0.y); u.y = pk2(f0.z, f0.w);
        u.z = pk2(f1.x, f1.y); u.w = pk2(f1.z, f1.w);
        a[mi] = __builtin_bit_cast(bf16x8, u);
      } else {
        a[mi] = *(const bf16x8*)(arow[mi] + kk * 32 * 2);
      }
    }
#pragma unroll
    for (int ni = 0; ni < 2; ++ni) {
      int row = wn + ni * 16 + lrow;
      int colb = kk * 64 + (lane >> 4) * 16;
      b[ni] = *(const bf16x8*)((char*)Bs + row * 384 + (colb ^ ((row & 7) << 4)));
    }
#pragma unroll
    for (int mi = 0; mi < 4; ++mi)
#pragma unroll
      for (int ni = 0; ni < 2; ++ni)
        acc[mi][ni] = __builtin_amdgcn_mfma_f32_16x16x32_bf16(a[mi], b[ni], acc[mi][ni], 0, 0, 0);
  }

  const int crow = (lane >> 4) * 4, ccol = lane & 15;
#pragma unroll
  for (int mi = 0; mi < 4; ++mi)
#pragma unroll
    for (int ni = 0; ni < 2; ++ni)
#pragma unroll
      for (int rr = 0; rr < 4; ++rr) {
        size_t off = (size_t)z * strideC +
                     (size_t)(m0 + wm + mi * 16 + crow + rr) * N + n0 + wn + ni * 16 + ccol;
        if (C_BF16) ((u16*)Cv)[off] = f2bf(acc[mi][ni][rr]);
        else        ((float*)Cv)[off] = acc[mi][ni][rr];
      }
}

// ---------------- depthwise 3x3 SAME conv, LDS-staged ----------------
__global__ __launch_bounds__(192) void dwconv_k(
    const u16* __restrict__ pre, const float* __restrict__ dwW,
    u16* __restrict__ qb, u16* __restrict__ kb, u16* __restrict__ vb,
    float* __restrict__ psum, int b0) {
  __shared__ __align__(16) u16 lds[2400 * 8];
  const int t = threadIdx.x;
  const int tile = blockIdx.x, sel = blockIdx.y, brel = blockIdx.z;
  const int h0 = (tile >> 4) * 8, w0 = (tile & 15) * 8;
  const int cg = t % 24, tw = t / 24;
  const int c = sel * 192 + cg * 8;

  float wgt[9][8];
#pragma unroll
  for (int tap = 0; tap < 9; ++tap) {
    float4 a = *(const float4*)&dwW[(size_t)tap * C3 + c];
    float4 b = *(const float4*)&dwW[(size_t)tap * C3 + c + 4];
    wgt[tap][0] = a.x; wgt[tap][1] = a.y; wgt[tap][2] = a.z; wgt[tap][3] = a.w;
    wgt[tap][4] = b.x; wgt[tap][5] = b.y; wgt[tap][6] = b.z; wgt[tap][7] = b.w;
  }

  const u16* src = pre + (size_t)brel * HWP * C3;
#pragma unroll
  for (int r = 0; r < 13; ++r) {
    int slot = t + r * 192;
    if (slot < 2400) {
      int pix = r * 8 + tw;
      int py = pix / 10, px = pix % 10;
      int gh = h0 - 1 + py, gw = w0 - 1 + px;
      uint4 v = make_uint4(0, 0, 0, 0);
      if ((unsigned)gh < 128u && (unsigned)gw < 128u)
        v = *(const uint4*)&src[(size_t)((gh << 7) + gw) * C3 + c];
      *(uint4*)&lds[slot * 8] = v;
    }
  }
  __syncthreads();

  float ssum[8] = {};
  u16* dstb = (sel == 0 ? qb : sel == 1 ? kb : vb) + (size_t)brel * PBF;
#pragma unroll
  for (int r = 0; r < 8; ++r) {
    float acc[8] = {};
#pragma unroll
    for (int dy = 0; dy < 3; ++dy)
#pragma unroll
      for (int dx = 0; dx < 3; ++dx) {
        uint4 v = *(const uint4*)&lds[(((r + dy) * 10 + tw + dx) * 24 + cg) * 8];
        const float* wg = wgt[dy * 3 + dx];
        acc[0] += bflo(v.x) * wg[0]; acc[1] += bfhi(v.x) * wg[1];
        acc[2] += bflo(v.y) * wg[2]; acc[3] += bfhi(v.y) * wg[3];
        acc[4] += bflo(v.z) * wg[4]; acc[5] += bfhi(v.z) * wg[5];
        acc[6] += bflo(v.w) * wg[6]; acc[7] += bfhi(v.w) * wg[7];
      }
    uint4 o;
    o.x = pk2(acc[0], acc[1]); o.y = pk2(acc[2], acc[3]);
    o.z = pk2(acc[4], acc[5]); o.w = pk2(acc[6], acc[7]);
    *(uint4*)&dstb[(size_t)(((h0 + r) << 7) + w0 + tw) * CIN + cg * 8] = o;
    if (sel < 2) {
#pragma unroll
      for (int i = 0; i < 8; ++i) ssum[i] += acc[i] * acc[i];
    }
  }

  if (sel < 2) {
    __syncthreads();
    float* fl = (float*)lds;
#pragma unroll
    for (int i = 0; i < 8; ++i) fl[tw * 192 + cg * 8 + i] = ssum[i];
    __syncthreads();
    float s = 0.f;
#pragma unroll
    for (int tw2 = 0; tw2 < 8; ++tw2) s += fl[tw2 * 192 + t];
    psum[(((size_t)sel * 8 + (b0 + brel)) * 192 + t) * 256 + tile] = s;
  }
}

// ---------------- reduce psum tiles -> rsqrt norms ----------------
__global__ __launch_bounds__(192) void rownorm2_k(
    const float* __restrict__ psum, float* __restrict__ rq, float* __restrict__ rk,
    int b0) {
  int sel = blockIdx.x, brel = blockIdx.y;
  int b = b0 + brel;
  int t = threadIdx.x;
  const float* p = psum + (((size_t)sel * 8 + b) * 192 + t) * 256;
  float s = 0.f;
#pragma unroll 4
  for (int i = 0; i < 256; i += 4) {
    float4 v = *(const float4*)&p[i];
    s += v.x + v.y + v.z + v.w;
  }
  (sel ? rk : rq)[b * CIN + t] = rsqrtf(fmaxf(s, 1e-12f));
}

// ---------------- QK^T partial: per (sc,n,brel) block, 48x48 partial over 256 s ----
__global__ __launch_bounds__(256) void qk_partial_k(
    const u16* __restrict__ qbuf, const u16* __restrict__ kbuf,
    float* __restrict__ partial, int b0) {
  int sc = blockIdx.x, n = blockIdx.y, brel = blockIdx.z;
  int b = b0 + brel;
  __shared__ float qs[48][QKPAD];
  __shared__ float ks[48][QKPAD];
  const u16* qp = qbuf + (size_t)brel * PBF + (size_t)n * CH * HWP;
  const u16* kp = kbuf + (size_t)brel * PBF + (size_t)n * CH * HWP;
  int t = threadIdx.x;
  int i0 = (t >> 4) * 3, j0 = (t & 15) * 3;
  float acc[3][3] = {};
  int sBeg = sc * 256;
  for (int s0 = sBeg; s0 < sBeg + 256; s0 += 64) {
    uint2 qv[3], kv[3];
#pragma unroll
    for (int rep = 0; rep < 3; ++rep) {
      int fi = t + rep * 256;
      int row = fi >> 4;
      int sv = (fi & 15) * 4;
      qv[rep] = *(const uint2*)&qp[(size_t)row * HWP + s0 + sv];
      kv[rep] = *(const uint2*)&kp[(size_t)row * HWP + s0 + sv];
    }
    __syncthreads();
#pragma unroll
    for (int rep = 0; rep < 3; ++rep) {
      int fi = t + rep * 256;
      int row = fi >> 4;
      int sv = (fi & 15) * 4;
      qs[row][sv + 0] = bflo(qv[rep].x); qs[row][sv + 1] = bfhi(qv[rep].x);
      qs[row][sv + 2] = bflo(qv[rep].y); qs[row][sv + 3] = bfhi(qv[rep].y);
      ks[row][sv + 0] = bflo(kv[rep].x); ks[row][sv + 1] = bfhi(kv[rep].x);
      ks[row][sv + 2] = bflo(kv[rep].y); ks[row][sv + 3] = bfhi(kv[rep].y);
    }
    __syncthreads();
#pragma unroll
    for (int s4 = 0; s4 < 16; ++s4) {
      float4 q0 = *(const float4*)&qs[i0 + 0][s4 * 4];
      float4 q1 = *(const float4*)&qs[i0 + 1][s4 * 4];
      float4 q2 = *(const float4*)&qs[i0 + 2][s4 * 4];
      float4 k0 = *(const float4*)&ks[j0 + 0][s4 * 4];
      float4 k1 = *(const float4*)&ks[j0 + 1][s4 * 4];
      float4 k2 = *(const float4*)&ks[j0 + 2][s4 * 4];
      acc[0][0] += q0.x*k0.x + q0.y*k0.y + q0.z*k0.z + q0.w*k0.w;
      acc[0][1] += q0.x*k1.x + q0.y*k1.y + q0.z*k1.z + q0.w*k1.w;
      acc[0][2] += q0.x*k2.x + q0.y*k2.y + q0.z*k2.z + q0.w*k2.w;
      acc[1][0] += q1.x*k0.x + q1.y*k0.y + q1.z*k0.z + q1.w*k0.w;
      acc[1][1] += q1.x*k1.x + q1.y*k1.y + q1.z*k1.z + q1.w*k1.w;
      acc[1][2] += q1.x*k2.x + q1.y*k2.y + q1.z*k2.z + q1.w*k2.w;
      acc[2][0] += q2.x*k0.x + q2.y*k0.y + q2.z*k0.z + q2.w*k0.w;
      acc[2][1] += q2.x*k1.x + q2.y*k1.y + q2.z*k1.z + q2.w*k1.w;
      acc[2][2] += q2.x*k2.x + q2.y*k2.y + q2.z*k2.z + q2.w*k2.w;
    }
    __syncthreads();
  }
#pragma unroll
  for (int ii = 0; ii < 3; ++ii)
#pragma unroll
    for (int jj = 0; jj < 3; ++jj)
      partial[((((size_t)b * NHD + n) * NS + sc) * CH + (i0 + ii)) * CH + (j0 + jj)] = acc[ii][jj];
}

// ---------------- reduce partials, scale, softmax over j ----------------
__global__ __launch_bounds__(64) void softmax_k(
    const float* __restrict__ partial, const float* __restrict__ rq, const float* __restrict__ rk,
    const float* __restrict__ temp, float* __restrict__ attn, int b0) {
  int i = blockIdx.x % CH;
  int n = (blockIdx.x / CH) % NHD;
  int brel = blockIdx.x / (CH * NHD);
  int b = b0 + brel;
  int j = threadIdx.x;
  float logit = -INFINITY;
  if (j < CH) {
    float s = 0.f;
#pragma unroll 8
    for (int sc = 0; sc < NS; ++sc)
      s += partial[((((size_t)b * NHD + n) * NS + sc) * CH + i) * CH + j];
    logit = s * rq[b * CIN + n * CH + i] * rk[b * CIN + n * CH + j] * temp[n];
  }
  float m = logit;
#pragma unroll
  for (int o = 32; o > 0; o >>= 1) m = fmaxf(m, __shfl_xor(m, o));
  float e = (j < CH) ? expf(logit - m) : 0.f;
  float sum = e;
#pragma unroll
  for (int o = 32; o > 0; o >>= 1) sum += __shfl_xor(sum, o);
  if (j < CH) attn[(((size_t)b * NHD + n) * CH + i) * CH + j] = e / sum;
}

// ---------------- O = attn * V (bf16 V in, bf16 O out) ----------------
__global__ __launch_bounds__(256) void av_k(
    const float* __restrict__ attn, const u16* __restrict__ vbuf,
    u16* __restrict__ obuf, int b0) {
  int st = blockIdx.x, n = blockIdx.y, brel = blockIdx.z;
  int b = b0 + brel;
  __shared__ float as_[CH * CH];
  int t = threadIdx.x;
  const float* ap = attn + ((size_t)b * NHD + n) * CH * CH;
#pragma unroll
  for (int r = 0; r < 9; ++r) as_[t + r * 256] = ap[t + r * 256];
  __syncthreads();
  int s = st * 512 + t * 2;
  const u16* vp = vbuf + (size_t)brel * PBF + (size_t)n * CH * HWP;
  float2 acc[CH];
#pragma unroll
  for (int d = 0; d < CH; ++d) { acc[d].x = 0.f; acc[d].y = 0.f; }
#pragma unroll 4
  for (int j4 = 0; j4 < 12; ++j4) {
    unsigned int u0 = *(const unsigned int*)&vp[(size_t)(j4 * 4 + 0) * HWP + s];
    unsigned int u1 = *(const unsigned int*)&vp[(size_t)(j4 * 4 + 1) * HWP + s];
    unsigned int u2 = *(const unsigned int*)&vp[(size_t)(j4 * 4 + 2) * HWP + s];
    unsigned int u3 = *(const unsigned int*)&vp[(size_t)(j4 * 4 + 3) * HWP + s];
    float2 v0 = make_float2(bflo(u0), bfhi(u0));
    float2 v1 = make_float2(bflo(u1), bfhi(u1));
    float2 v2 = make_float2(bflo(u2), bfhi(u2));
    float2 v3 = make_float2(bflo(u3), bfhi(u3));
#pragma unroll
    for (int d = 0; d < CH; ++d) {
      float4 a4 = *(const float4*)&as_[d * CH + j4 * 4];
      acc[d].x += a4.x * v0.x + a4.y * v1.x + a4.z * v2.x + a4.w * v3.x;
      acc[d].y += a4.x * v0.y + a4.y * v1.y + a4.z * v2.y + a4.w * v3.y;
    }
  }
  u16* op = obuf + (size_t)brel * PBF + (size_t)n * CH * HWP;
#pragma unroll
  for (int d = 0; d < CH; ++d) {
    ushort2 o; o.x = f2bf(acc[d].x); o.y = f2bf(acc[d].y);
    *(ushort2*)&op[(size_t)d * HWP + s] = o;
  }
}

extern "C" void kernel_launch(void* const* d_in, const int* in_sizes, int n_in,
                              void* d_out, int out_size, void* d_ws, size_t ws_size,
                              hipStream_t stream) {
  const float* x      = (const float*)d_in[0];
  const float* qkv_w  = (const float*)d_in[1];
  const float* dw_w   = (const float*)d_in[2];
  const float* proj_w = (const float*)d_in[3];
  const float* temp   = (const float*)d_in[4];
  float* out = (float*)d_out;

  // fixed buffers
  float* rq      = (float*)d_ws;                        // 8*192
  float* rk      = rq + 8 * CIN;                        // 8*192
  float* attn    = rk + 8 * CIN;                        // 8*4*48*48
  float* partial = attn + 8 * NHD * CH * CH;            // 8*4*NS*48*48
  float* psum    = partial + (size_t)8 * NHD * NS * CH * CH;  // 2*8*192*256
  u16* qkvwT  = (u16*)(psum + (size_t)2 * 8 * 192 * 256);
  u16* projwT = qkvwT + (size_t)C3 * CIN;
  char* bufbase = (char*)(projwT + (size_t)CIN * CIN);
  size_t off = (size_t)(bufbase - (char*)d_ws);
  off = (off + 255) & ~(size_t)255;

  // per-batch: qkv_pre bf16 + q,k,v,o bf16
  const size_t perBatchBytes = (size_t)HWP * C3 * 2 + 4 * (size_t)PBF * 2;
  size_t avail = ws_size > off ? ws_size - off : 0;
  int nb = (int)(avail / perBatchBytes);
  if (nb < 1) nb = 1;
  if (nb > 8) nb = 8;

  u16* qkv_pre = (u16*)((char*)d_ws + off);
  u16* qbuf = qkv_pre + (size_t)nb * HWP * C3;
  u16* kbuf = qbuf + (size_t)nb * PBF;
  u16* vbuf = kbuf + (size_t)nb * PBF;
  u16* obuf = vbuf + (size_t)nb * PBF;

  convert_w_k<<<dim3((C3 * CIN + CIN * CIN + 255) / 256), 256, 0, stream>>>(
      qkv_w, proj_w, qkvwT, projwT);

  for (int b0 = 0; b0 < 8; b0 += nb) {
    int nbc = (8 - b0) < nb ? (8 - b0) : nb;
    int M = nbc * HWP;
    // 1) qkv = x @ qkv_w  (fp32 A fused-convert, bf16 C)
    gemm_skinny<true, true><<<dim3((M / 128) * (C3 / 64), 1, 1), 256, 0, stream>>>(
        x + (size_t)b0 * HWP * CIN, qkvwT, qkv_pre, C3, 0, 0, 0);
    // 2) depthwise 3x3 (LDS-staged) + split q/k/v + fused q/k sq-sum partials
    dwconv_k<<<dim3(256, 3, nbc), 192, 0, stream>>>(
        qkv_pre, dw_w, qbuf, kbuf, vbuf, psum, b0);
    // 3) reduce partials -> rsqrt norms
    rownorm2_k<<<dim3(2, nbc), 192, 0, stream>>>(psum, rq, rk, b0);
    // 4) QK^T partials
    qk_partial_k<<<dim3(NS, NHD, nbc), 256, 0, stream>>>(qbuf, kbuf, partial, b0);
    // 5) reduce + scale + softmax
    softmax_k<<<dim3(nbc * NHD * CH), 64, 0, stream>>>(partial, rq, rk, temp, attn, b0);
    // 6) O = attn @ V
    av_k<<<dim3(HWP / 512, NHD, nbc), 256, 0, stream>>>(attn, vbuf, obuf, b0);
    // 7) out = O @ proj_w  (bf16 A direct, fp32 C)
    gemm_skinny<false, false><<<dim3((M / 128) * (CIN / 64), 1, 1), 256, 0, stream>>>(
        obuf, projwT, out + (size_t)b0 * HWP * CIN, CIN, 0, 0, 0);
  }
}

// Round 9
// 411.393 us; speedup vs baseline: 1.2315x; 1.2315x over previous
//
#include <hip/hip_runtime.h>
#include <math.h>

#define HWP 16384   // pixels per image (128*128)
#define CIN 192
#define C3  576
#define CH  48      // c_head
#define NHD 4       // heads
#define NS  64      // s-partitions for QK^T partial reduction (256 s each)
#define PBF 3145728 // per-batch elems of one [192,16384] matrix (= 16384*192)
#define QKPAD 68    // LDS row stride for qk_partial fp32 tiles
#define KG  192     // GEMM K (both GEMMs)

typedef unsigned short u16;
typedef __attribute__((ext_vector_type(8))) short bf16x8;
typedef __attribute__((ext_vector_type(4))) float f32x4;

__device__ __forceinline__ u16 f2bf(float f) {
  unsigned int u = __builtin_bit_cast(unsigned int, f);
  u = (u + 0x7FFFu + ((u >> 16) & 1u)) >> 16;
  return (u16)u;
}
__device__ __forceinline__ float bflo(unsigned int u) {
  return __builtin_bit_cast(float, u << 16);
}
__device__ __forceinline__ float bfhi(unsigned int u) {
  return __builtin_bit_cast(float, u & 0xFFFF0000u);
}
__device__ __forceinline__ unsigned pk2(float a, float b) {
  return (unsigned)f2bf(a) | ((unsigned)f2bf(b) << 16);
}

// ---------------- convert x (fp32) -> bf16, 8 elems/thread ----------------
__global__ __launch_bounds__(256) void convert_x_k(
    const float* __restrict__ in, u16* __restrict__ out) {
  size_t base = ((size_t)blockIdx.x * 256 + threadIdx.x) * 8;
  float4 a = *(const float4*)&in[base];
  float4 b = *(const float4*)&in[base + 4];
  uint4 o;
  o.x = pk2(a.x, a.y); o.y = pk2(a.z, a.w);
  o.z = pk2(b.x, b.y); o.w = pk2(b.z, b.w);
  *(uint4*)&out[base] = o;
}

// ---------------- convert + transpose weights -> bf16 [N][K] ----------------
__global__ __launch_bounds__(256) void convert_w_k(
    const float* __restrict__ qkvW, const float* __restrict__ projW,
    u16* __restrict__ qkvWT, u16* __restrict__ projWT) {
  int idx = blockIdx.x * 256 + threadIdx.x;
  if (idx < C3 * CIN) {
    int n = idx / CIN, k = idx % CIN;
    qkvWT[idx] = f2bf(qkvW[(size_t)k * C3 + n]);
  } else {
    int i2 = idx - C3 * CIN;
    if (i2 < CIN * CIN) {
      int n = i2 / CIN, k = i2 % CIN;
      projWT[i2] = f2bf(projW[(size_t)k * CIN + n]);
    }
  }
}

// ---------------- single-stage bf16 MFMA GEMM, whole K=192 in LDS ----------------
// C[M,N] = A[M,K] * BT[N,K]^T. BM=128 BN=64 BK=192; 256 thr (4 waves, wave=64x32).
// 18 upfront global uint4 loads -> swizzled ds_write -> ONE barrier ->
// 36 conflict-free ds_read_b128 + 48 MFMA per wave, no further waits.
// LDS 72KB -> 2 blocks/CU; co-resident block staging overlaps compute.
template <bool C_BF16>
__global__ __launch_bounds__(256) void gemm1(
    const u16* __restrict__ A, const u16* __restrict__ BT, void* __restrict__ Cv,
    int N) {
  __shared__ __align__(16) u16 As[128 * KG];
  __shared__ __align__(16) u16 Bs[64 * KG];
  const int t = threadIdx.x;
  const int lane = t & 63, wave = t >> 6;
  const int nT = N >> 6;
  const int nwg = gridDim.x;
  const int bid = blockIdx.x;
  const int q = nwg >> 3, r = nwg & 7;
  const int xcd = bid & 7, idx = bid >> 3;
  const int swz = (xcd < r) ? (xcd * (q + 1) + idx)
                            : (r * (q + 1) + (xcd - r) * q + idx);
  const int m0 = (swz / nT) * 128, n0 = (swz % nT) * 64;
  const int wm = (wave >> 1) * 64, wn = (wave & 1) * 32;

  // ---- batched global loads (all in flight before any LDS write) ----
  uint4 va[12], vb[6];
#pragma unroll
  for (int i = 0; i < 12; ++i) {
    int slot = t + i * 256;
    int row = slot / 24, c = slot % 24;       // 24 x 16B per 384B row
    va[i] = *(const uint4*)&A[(size_t)(m0 + row) * KG + c * 8];
  }
#pragma unroll
  for (int i = 0; i < 6; ++i) {
    int slot = t + i * 256;
    int row = slot / 24, c = slot % 24;
    vb[i] = *(const uint4*)&BT[(size_t)(n0 + row) * KG + c * 8];
  }
  // ---- swizzled LDS writes ----
#pragma unroll
  for (int i = 0; i < 12; ++i) {
    int slot = t + i * 256;
    int row = slot / 24, cb = (slot % 24) * 16;
    *(uint4*)((char*)As + row * 384 + (cb ^ ((row & 7) << 4))) = va[i];
  }
#pragma unroll
  for (int i = 0; i < 6; ++i) {
    int slot = t + i * 256;
    int row = slot / 24, cb = (slot % 24) * 16;
    *(uint4*)((char*)Bs + row * 384 + (cb ^ ((row & 7) << 4))) = vb[i];
  }
  __syncthreads();

  f32x4 acc[4][2];
#pragma unroll
  for (int mi = 0; mi < 4; ++mi)
#pragma unroll
    for (int ni = 0; ni < 2; ++ni) acc[mi][ni] = (f32x4){0.f, 0.f, 0.f, 0.f};

  const int lrow = lane & 15;
  const int lg16 = (lane >> 4) * 16;          // byte offset of 8-elem k-group
#pragma unroll
  for (int kk = 0; kk < 6; ++kk) {
    const int colb = kk * 64 + lg16;
    bf16x8 a[4], b[2];
#pragma unroll
    for (int mi = 0; mi < 4; ++mi) {
      int row = wm + mi * 16 + lrow;
      a[mi] = *(const bf16x8*)((char*)As + row * 384 + (colb ^ ((row & 7) << 4)));
    }
#pragma unroll
    for (int ni = 0; ni < 2; ++ni) {
      int row = wn + ni * 16 + lrow;
      b[ni] = *(const bf16x8*)((char*)Bs + row * 384 + (colb ^ ((row & 7) << 4)));
    }
#pragma unroll
    for (int mi = 0; mi < 4; ++mi)
#pragma unroll
      for (int ni = 0; ni < 2; ++ni)
        acc[mi][ni] = __builtin_amdgcn_mfma_f32_16x16x32_bf16(a[mi], b[ni], acc[mi][ni], 0, 0, 0);
  }

  const int crow = (lane >> 4) * 4, ccol = lane & 15;
#pragma unroll
  for (int mi = 0; mi < 4; ++mi)
#pragma unroll
    for (int ni = 0; ni < 2; ++ni)
#pragma unroll
      for (int rr = 0; rr < 4; ++rr) {
        size_t off = (size_t)(m0 + wm + mi * 16 + crow + rr) * N + n0 + wn + ni * 16 + ccol;
        if (C_BF16) ((u16*)Cv)[off] = f2bf(acc[mi][ni][rr]);
        else        ((float*)Cv)[off] = acc[mi][ni][rr];
      }
}

// ---------------- depthwise 3x3 SAME conv, LDS-staged ----------------
__global__ __launch_bounds__(192) void dwconv_k(
    const u16* __restrict__ pre, const float* __restrict__ dwW,
    u16* __restrict__ qb, u16* __restrict__ kb, u16* __restrict__ vb,
    float* __restrict__ psum, int b0) {
  __shared__ __align__(16) u16 lds[2400 * 8];
  const int t = threadIdx.x;
  const int tile = blockIdx.x, sel = blockIdx.y, brel = blockIdx.z;
  const int h0 = (tile >> 4) * 8, w0 = (tile & 15) * 8;
  const int cg = t % 24, tw = t / 24;
  const int c = sel * 192 + cg * 8;

  float wgt[9][8];
#pragma unroll
  for (int tap = 0; tap < 9; ++tap) {
    float4 a = *(const float4*)&dwW[(size_t)tap * C3 + c];
    float4 b = *(const float4*)&dwW[(size_t)tap * C3 + c + 4];
    wgt[tap][0] = a.x; wgt[tap][1] = a.y; wgt[tap][2] = a.z; wgt[tap][3] = a.w;
    wgt[tap][4] = b.x; wgt[tap][5] = b.y; wgt[tap][6] = b.z; wgt[tap][7] = b.w;
  }

  const u16* src = pre + (size_t)brel * HWP * C3;
#pragma unroll
  for (int r = 0; r < 13; ++r) {
    int slot = t + r * 192;
    if (slot < 2400) {
      int pix = r * 8 + tw;
      int py = pix / 10, px = pix % 10;
      int gh = h0 - 1 + py, gw = w0 - 1 + px;
      uint4 v = make_uint4(0, 0, 0, 0);
      if ((unsigned)gh < 128u && (unsigned)gw < 128u)
        v = *(const uint4*)&src[(size_t)((gh << 7) + gw) * C3 + c];
      *(uint4*)&lds[slot * 8] = v;
    }
  }
  __syncthreads();

  float ssum[8] = {};
  u16* dstb = (sel == 0 ? qb : sel == 1 ? kb : vb) + (size_t)brel * PBF;
#pragma unroll
  for (int r = 0; r < 8; ++r) {
    float acc[8] = {};
#pragma unroll
    for (int dy = 0; dy < 3; ++dy)
#pragma unroll
      for (int dx = 0; dx < 3; ++dx) {
        uint4 v = *(const uint4*)&lds[(((r + dy) * 10 + tw + dx) * 24 + cg) * 8];
        const float* wg = wgt[dy * 3 + dx];
        acc[0] += bflo(v.x) * wg[0]; acc[1] += bfhi(v.x) * wg[1];
        acc[2] += bflo(v.y) * wg[2]; acc[3] += bfhi(v.y) * wg[3];
        acc[4] += bflo(v.z) * wg[4]; acc[5] += bfhi(v.z) * wg[5];
        acc[6] += bflo(v.w) * wg[6]; acc[7] += bfhi(v.w) * wg[7];
      }
    uint4 o;
    o.x = pk2(acc[0], acc[1]); o.y = pk2(acc[2], acc[3]);
    o.z = pk2(acc[4], acc[5]); o.w = pk2(acc[6], acc[7]);
    *(uint4*)&dstb[(size_t)(((h0 + r) << 7) + w0 + tw) * CIN + cg * 8] = o;
    if (sel < 2) {
#pragma unroll
      for (int i = 0; i < 8; ++i) ssum[i] += acc[i] * acc[i];
    }
  }

  if (sel < 2) {
    __syncthreads();
    float* fl = (float*)lds;
#pragma unroll
    for (int i = 0; i < 8; ++i) fl[tw * 192 + cg * 8 + i] = ssum[i];
    __syncthreads();
    float s = 0.f;
#pragma unroll
    for (int tw2 = 0; tw2 < 8; ++tw2) s += fl[tw2 * 192 + t];
    psum[(((size_t)sel * 8 + (b0 + brel)) * 192 + t) * 256 + tile] = s;
  }
}

// ---------------- reduce psum tiles -> rsqrt norms ----------------
__global__ __launch_bounds__(192) void rownorm2_k(
    const float* __restrict__ psum, float* __restrict__ rq, float* __restrict__ rk,
    int b0) {
  int sel = blockIdx.x, brel = blockIdx.y;
  int b = b0 + brel;
  int t = threadIdx.x;
  const float* p = psum + (((size_t)sel * 8 + b) * 192 + t) * 256;
  float s = 0.f;
#pragma unroll 4
  for (int i = 0; i < 256; i += 4) {
    float4 v = *(const float4*)&p[i];
    s += v.x + v.y + v.z + v.w;
  }
  (sel ? rk : rq)[b * CIN + t] = rsqrtf(fmaxf(s, 1e-12f));
}

// ---------------- QK^T partial: per (sc,n,brel) block, 48x48 partial over 256 s ----
__global__ __launch_bounds__(256) void qk_partial_k(
    const u16* __restrict__ qbuf, const u16* __restrict__ kbuf,
    float* __restrict__ partial, int b0) {
  int sc = blockIdx.x, n = blockIdx.y, brel = blockIdx.z;
  int b = b0 + brel;
  __shared__ float qs[48][QKPAD];
  __shared__ float ks[48][QKPAD];
  const u16* qp = qbuf + (size_t)brel * PBF + (size_t)n * CH * HWP;
  const u16* kp = kbuf + (size_t)brel * PBF + (size_t)n * CH * HWP;
  int t = threadIdx.x;
  int i0 = (t >> 4) * 3, j0 = (t & 15) * 3;
  float acc[3][3] = {};
  int sBeg = sc * 256;
  for (int s0 = sBeg; s0 < sBeg + 256; s0 += 64) {
    uint2 qv[3], kv[3];
#pragma unroll
    for (int rep = 0; rep < 3; ++rep) {
      int fi = t + rep * 256;
      int row = fi >> 4;
      int sv = (fi & 15) * 4;
      qv[rep] = *(const uint2*)&qp[(size_t)row * HWP + s0 + sv];
      kv[rep] = *(const uint2*)&kp[(size_t)row * HWP + s0 + sv];
    }
    __syncthreads();
#pragma unroll
    for (int rep = 0; rep < 3; ++rep) {
      int fi = t + rep * 256;
      int row = fi >> 4;
      int sv = (fi & 15) * 4;
      qs[row][sv + 0] = bflo(qv[rep].x); qs[row][sv + 1] = bfhi(qv[rep].x);
      qs[row][sv + 2] = bflo(qv[rep].y); qs[row][sv + 3] = bfhi(qv[rep].y);
      ks[row][sv + 0] = bflo(kv[rep].x); ks[row][sv + 1] = bfhi(kv[rep].x);
      ks[row][sv + 2] = bflo(kv[rep].y); ks[row][sv + 3] = bfhi(kv[rep].y);
    }
    __syncthreads();
#pragma unroll
    for (int s4 = 0; s4 < 16; ++s4) {
      float4 q0 = *(const float4*)&qs[i0 + 0][s4 * 4];
      float4 q1 = *(const float4*)&qs[i0 + 1][s4 * 4];
      float4 q2 = *(const float4*)&qs[i0 + 2][s4 * 4];
      float4 k0 = *(const float4*)&ks[j0 + 0][s4 * 4];
      float4 k1 = *(const float4*)&ks[j0 + 1][s4 * 4];
      float4 k2 = *(const float4*)&ks[j0 + 2][s4 * 4];
      acc[0][0] += q0.x*k0.x + q0.y*k0.y + q0.z*k0.z + q0.w*k0.w;
      acc[0][1] += q0.x*k1.x + q0.y*k1.y + q0.z*k1.z + q0.w*k1.w;
      acc[0][2] += q0.x*k2.x + q0.y*k2.y + q0.z*k2.z + q0.w*k2.w;
      acc[1][0] += q1.x*k0.x + q1.y*k0.y + q1.z*k0.z + q1.w*k0.w;
      acc[1][1] += q1.x*k1.x + q1.y*k1.y + q1.z*k1.z + q1.w*k1.w;
      acc[1][2] += q1.x*k2.x + q1.y*k2.y + q1.z*k2.z + q1.w*k2.w;
      acc[2][0] += q2.x*k0.x + q2.y*k0.y + q2.z*k0.z + q2.w*k0.w;
      acc[2][1] += q2.x*k1.x + q2.y*k1.y + q2.z*k1.z + q2.w*k1.w;
      acc[2][2] += q2.x*k2.x + q2.y*k2.y + q2.z*k2.z + q2.w*k2.w;
    }
    __syncthreads();
  }
#pragma unroll
  for (int ii = 0; ii < 3; ++ii)
#pragma unroll
    for (int jj = 0; jj < 3; ++jj)
      partial[((((size_t)b * NHD + n) * NS + sc) * CH + (i0 + ii)) * CH + (j0 + jj)] = acc[ii][jj];
}

// ---------------- reduce partials, scale, softmax over j ----------------
__global__ __launch_bounds__(64) void softmax_k(
    const float* __restrict__ partial, const float* __restrict__ rq, const float* __restrict__ rk,
    const float* __restrict__ temp, float* __restrict__ attn, int b0) {
  int i = blockIdx.x % CH;
  int n = (blockIdx.x / CH) % NHD;
  int brel = blockIdx.x / (CH * NHD);
  int b = b0 + brel;
  int j = threadIdx.x;
  float logit = -INFINITY;
  if (j < CH) {
    float s = 0.f;
#pragma unroll 8
    for (int sc = 0; sc < NS; ++sc)
      s += partial[((((size_t)b * NHD + n) * NS + sc) * CH + i) * CH + j];
    logit = s * rq[b * CIN + n * CH + i] * rk[b * CIN + n * CH + j] * temp[n];
  }
  float m = logit;
#pragma unroll
  for (int o = 32; o > 0; o >>= 1) m = fmaxf(m, __shfl_xor(m, o));
  float e = (j < CH) ? expf(logit - m) : 0.f;
  float sum = e;
#pragma unroll
  for (int o = 32; o > 0; o >>= 1) sum += __shfl_xor(sum, o);
  if (j < CH) attn[(((size_t)b * NHD + n) * CH + i) * CH + j] = e / sum;
}

// ---------------- O = attn * V (bf16 V in, bf16 O out) ----------------
__global__ __launch_bounds__(256) void av_k(
    const float* __restrict__ attn, const u16* __restrict__ vbuf,
    u16* __restrict__ obuf, int b0) {
  int st = blockIdx.x, n = blockIdx.y, brel = blockIdx.z;
  int b = b0 + brel;
  __shared__ float as_[CH * CH];
  int t = threadIdx.x;
  const float* ap = attn + ((size_t)b * NHD + n) * CH * CH;
#pragma unroll
  for (int r = 0; r < 9; ++r) as_[t + r * 256] = ap[t + r * 256];
  __syncthreads();
  int s = st * 512 + t * 2;
  const u16* vp = vbuf + (size_t)brel * PBF + (size_t)n * CH * HWP;
  float2 acc[CH];
#pragma unroll
  for (int d = 0; d < CH; ++d) { acc[d].x = 0.f; acc[d].y = 0.f; }
#pragma unroll 4
  for (int j4 = 0; j4 < 12; ++j4) {
    unsigned int u0 = *(const unsigned int*)&vp[(size_t)(j4 * 4 + 0) * HWP + s];
    unsigned int u1 = *(const unsigned int*)&vp[(size_t)(j4 * 4 + 1) * HWP + s];
    unsigned int u2 = *(const unsigned int*)&vp[(size_t)(j4 * 4 + 2) * HWP + s];
    unsigned int u3 = *(const unsigned int*)&vp[(size_t)(j4 * 4 + 3) * HWP + s];
    float2 v0 = make_float2(bflo(u0), bfhi(u0));
    float2 v1 = make_float2(bflo(u1), bfhi(u1));
    float2 v2 = make_float2(bflo(u2), bfhi(u2));
    float2 v3 = make_float2(bflo(u3), bfhi(u3));
#pragma unroll
    for (int d = 0; d < CH; ++d) {
      float4 a4 = *(const float4*)&as_[d * CH + j4 * 4];
      acc[d].x += a4.x * v0.x + a4.y * v1.x + a4.z * v2.x + a4.w * v3.x;
      acc[d].y += a4.x * v0.y + a4.y * v1.y + a4.z * v2.y + a4.w * v3.y;
    }
  }
  u16* op = obuf + (size_t)brel * PBF + (size_t)n * CH * HWP;
#pragma unroll
  for (int d = 0; d < CH; ++d) {
    ushort2 o; o.x = f2bf(acc[d].x); o.y = f2bf(acc[d].y);
    *(ushort2*)&op[(size_t)d * HWP + s] = o;
  }
}

extern "C" void kernel_launch(void* const* d_in, const int* in_sizes, int n_in,
                              void* d_out, int out_size, void* d_ws, size_t ws_size,
                              hipStream_t stream) {
  const float* x      = (const float*)d_in[0];
  const float* qkv_w  = (const float*)d_in[1];
  const float* dw_w   = (const float*)d_in[2];
  const float* proj_w = (const float*)d_in[3];
  const float* temp   = (const float*)d_in[4];
  float* out = (float*)d_out;

  // fixed buffers
  float* rq      = (float*)d_ws;                        // 8*192
  float* rk      = rq + 8 * CIN;                        // 8*192
  float* attn    = rk + 8 * CIN;                        // 8*4*48*48
  float* partial = attn + 8 * NHD * CH * CH;            // 8*4*NS*48*48
  float* psum    = partial + (size_t)8 * NHD * NS * CH * CH;  // 2*8*192*256
  u16* qkvwT  = (u16*)(psum + (size_t)2 * 8 * 192 * 256);
  u16* projwT = qkvwT + (size_t)C3 * CIN;
  u16* xbf    = projwT + (size_t)CIN * CIN;             // 8*HWP*192 bf16
  char* bufbase = (char*)(xbf + (size_t)8 * HWP * CIN);
  size_t off = (size_t)(bufbase - (char*)d_ws);
  off = (off + 255) & ~(size_t)255;

  // per-batch: qkv_pre bf16 + q,k,v,o bf16
  const size_t perBatchBytes = (size_t)HWP * C3 * 2 + 4 * (size_t)PBF * 2;
  size_t avail = ws_size > off ? ws_size - off : 0;
  int nb = (int)(avail / perBatchBytes);
  if (nb < 1) nb = 1;
  if (nb > 8) nb = 8;

  u16* qkv_pre = (u16*)((char*)d_ws + off);
  u16* qbuf = qkv_pre + (size_t)nb * HWP * C3;
  u16* kbuf = qbuf + (size_t)nb * PBF;
  u16* vbuf = kbuf + (size_t)nb * PBF;
  u16* obuf = vbuf + (size_t)nb * PBF;

  convert_x_k<<<dim3((8 * HWP * CIN) / 2048), 256, 0, stream>>>(x, xbf);
  convert_w_k<<<dim3((C3 * CIN + CIN * CIN + 255) / 256), 256, 0, stream>>>(
      qkv_w, proj_w, qkvwT, projwT);

  for (int b0 = 0; b0 < 8; b0 += nb) {
    int nbc = (8 - b0) < nb ? (8 - b0) : nb;
    int M = nbc * HWP;
    // 1) qkv = x @ qkv_w  (bf16 A, bf16 C)
    gemm1<true><<<dim3((M / 128) * (C3 / 64)), 256, 0, stream>>>(
        xbf + (size_t)b0 * HWP * CIN, qkvwT, qkv_pre, C3);
    // 2) depthwise 3x3 (LDS-staged) + split q/k/v + fused q/k sq-sum partials
    dwconv_k<<<dim3(256, 3, nbc), 192, 0, stream>>>(
        qkv_pre, dw_w, qbuf, kbuf, vbuf, psum, b0);
    // 3) reduce partials -> rsqrt norms
    rownorm2_k<<<dim3(2, nbc), 192, 0, stream>>>(psum, rq, rk, b0);
    // 4) QK^T partials
    qk_partial_k<<<dim3(NS, NHD, nbc), 256, 0, stream>>>(qbuf, kbuf, partial, b0);
    // 5) reduce + scale + softmax
    softmax_k<<<dim3(nbc * NHD * CH), 64, 0, stream>>>(partial, rq, rk, temp, attn, b0);
    // 6) O = attn @ V
    av_k<<<dim3(HWP / 512, NHD, nbc), 256, 0, stream>>>(attn, vbuf, obuf, b0);
    // 7) out = O @ proj_w  (bf16 A, fp32 C)
    gemm1<false><<<dim3((M / 128) * (CIN / 64)), 256, 0, stream>>>(
        obuf, projwT, out + (size_t)b0 * HWP * CIN, CIN);
  }
}

// Round 10
// 355.613 us; speedup vs baseline: 1.4246x; 1.1569x over previous
//
#include <hip/hip_runtime.h>
#include <math.h>

#define HWP 16384   // pixels per image (128*128)
#define CIN 192
#define C3  576
#define CH  48      // c_head
#define NHD 4       // heads
#define NS  32      // s-partitions for QK^T partial reduction (512 s each)
#define PBF 3145728 // per-batch elems of one [192,16384] matrix (= 16384*192)
#define KG  192     // GEMM K (both GEMMs)

typedef unsigned short u16;
typedef __attribute__((ext_vector_type(8))) short bf16x8;
typedef __attribute__((ext_vector_type(4))) float f32x4;

__device__ __forceinline__ u16 f2bf(float f) {
  unsigned int u = __builtin_bit_cast(unsigned int, f);
  u = (u + 0x7FFFu + ((u >> 16) & 1u)) >> 16;
  return (u16)u;
}
__device__ __forceinline__ float bflo(unsigned int u) {
  return __builtin_bit_cast(float, u << 16);
}
__device__ __forceinline__ float bfhi(unsigned int u) {
  return __builtin_bit_cast(float, u & 0xFFFF0000u);
}
__device__ __forceinline__ unsigned pk2(float a, float b) {
  return (unsigned)f2bf(a) | ((unsigned)f2bf(b) << 16);
}

// ---------------- convert + transpose weights -> bf16 [N][K] ----------------
__global__ __launch_bounds__(256) void convert_w_k(
    const float* __restrict__ qkvW, const float* __restrict__ projW,
    u16* __restrict__ qkvWT, u16* __restrict__ projWT) {
  int idx = blockIdx.x * 256 + threadIdx.x;
  if (idx < C3 * CIN) {
    int n = idx / CIN, k = idx % CIN;
    qkvWT[idx] = f2bf(qkvW[(size_t)k * C3 + n]);
  } else {
    int i2 = idx - C3 * CIN;
    if (i2 < CIN * CIN) {
      int n = i2 / CIN, k = i2 % CIN;
      projWT[i2] = f2bf(projW[(size_t)k * CIN + n]);
    }
  }
}

// ---------------- single-stage bf16 MFMA GEMM, whole K=192 in LDS ----------------
// C[M,N] = A[M,K] * BT[N,K]^T. BM=128 BN=64 BK=192; 256 thr (4 waves, wave=64x32).
// Batched upfront global loads -> swizzled ds_write -> ONE barrier ->
// 36 conflict-free ds_read_b128 + 48 MFMA per wave, no further waits.
// A_F32: A is fp32, converted to bf16 in-register during staging.
template <bool A_F32, bool C_BF16>
__global__ __launch_bounds__(256) void gemm1(
    const void* __restrict__ Av, const u16* __restrict__ BT, void* __restrict__ Cv,
    int N) {
  __shared__ __align__(16) u16 As[128 * KG];
  __shared__ __align__(16) u16 Bs[64 * KG];
  const int t = threadIdx.x;
  const int lane = t & 63, wave = t >> 6;
  const int nT = N >> 6;
  const int nwg = gridDim.x;
  const int bid = blockIdx.x;
  const int q = nwg >> 3, r = nwg & 7;
  const int xcd = bid & 7, idx = bid >> 3;
  const int swz = (xcd < r) ? (xcd * (q + 1) + idx)
                            : (r * (q + 1) + (xcd - r) * q + idx);
  const int m0 = (swz / nT) * 128, n0 = (swz % nT) * 64;
  const int wm = (wave >> 1) * 64, wn = (wave & 1) * 32;

  // ---- batched global loads (all in flight before any LDS write) ----
  uint4 va[12], vb[6];
#pragma unroll
  for (int i = 0; i < 12; ++i) {
    int slot = t + i * 256;
    int row = slot / 24, c = slot % 24;       // 24 x 8-elem groups per row
    if (A_F32) {
      const float* p = (const float*)Av + (size_t)(m0 + row) * KG + c * 8;
      float4 f0 = *(const float4*)p;
      float4 f1 = *(const float4*)(p + 4);
      va[i].x = pk2(f0.x, f0.y); va[i].y = pk2(f0.z, f0.w);
      va[i].z = pk2(f1.x, f1.y); va[i].w = pk2(f1.z, f1.w);
    } else {
      va[i] = *(const uint4*)((const u16*)Av + (size_t)(m0 + row) * KG + c * 8);
    }
  }
#pragma unroll
  for (int i = 0; i < 6; ++i) {
    int slot = t + i * 256;
    int row = slot / 24, c = slot % 24;
    vb[i] = *(const uint4*)&BT[(size_t)(n0 + row) * KG + c * 8];
  }
  // ---- swizzled LDS writes ----
#pragma unroll
  for (int i = 0; i < 12; ++i) {
    int slot = t + i * 256;
    int row = slot / 24, cb = (slot % 24) * 16;
    *(uint4*)((char*)As + row * 384 + (cb ^ ((row & 7) << 4))) = va[i];
  }
#pragma unroll
  for (int i = 0; i < 6; ++i) {
    int slot = t + i * 256;
    int row = slot / 24, cb = (slot % 24) * 16;
    *(uint4*)((char*)Bs + row * 384 + (cb ^ ((row & 7) << 4))) = vb[i];
  }
  __syncthreads();

  f32x4 acc[4][2];
#pragma unroll
  for (int mi = 0; mi < 4; ++mi)
#pragma unroll
    for (int ni = 0; ni < 2; ++ni) acc[mi][ni] = (f32x4){0.f, 0.f, 0.f, 0.f};

  const int lrow = lane & 15;
  const int lg16 = (lane >> 4) * 16;          // byte offset of 8-elem k-group
#pragma unroll
  for (int kk = 0; kk < 6; ++kk) {
    const int colb = kk * 64 + lg16;
    bf16x8 a[4], b[2];
#pragma unroll
    for (int mi = 0; mi < 4; ++mi) {
      int row = wm + mi * 16 + lrow;
      a[mi] = *(const bf16x8*)((char*)As + row * 384 + (colb ^ ((row & 7) << 4)));
    }
#pragma unroll
    for (int ni = 0; ni < 2; ++ni) {
      int row = wn + ni * 16 + lrow;
      b[ni] = *(const bf16x8*)((char*)Bs + row * 384 + (colb ^ ((row & 7) << 4)));
    }
#pragma unroll
    for (int mi = 0; mi < 4; ++mi)
#pragma unroll
      for (int ni = 0; ni < 2; ++ni)
        acc[mi][ni] = __builtin_amdgcn_mfma_f32_16x16x32_bf16(a[mi], b[ni], acc[mi][ni], 0, 0, 0);
  }

  const int crow = (lane >> 4) * 4, ccol = lane & 15;
#pragma unroll
  for (int mi = 0; mi < 4; ++mi)
#pragma unroll
    for (int ni = 0; ni < 2; ++ni)
#pragma unroll
      for (int rr = 0; rr < 4; ++rr) {
        size_t off = (size_t)(m0 + wm + mi * 16 + crow + rr) * N + n0 + wn + ni * 16 + ccol;
        if (C_BF16) ((u16*)Cv)[off] = f2bf(acc[mi][ni][rr]);
        else        ((float*)Cv)[off] = acc[mi][ni][rr];
      }
}

// ---------------- depthwise 3x3 SAME conv, LDS-staged ----------------
__global__ __launch_bounds__(192) void dwconv_k(
    const u16* __restrict__ pre, const float* __restrict__ dwW,
    u16* __restrict__ qb, u16* __restrict__ kb, u16* __restrict__ vb,
    float* __restrict__ psum, int b0) {
  __shared__ __align__(16) u16 lds[2400 * 8];
  const int t = threadIdx.x;
  const int tile = blockIdx.x, sel = blockIdx.y, brel = blockIdx.z;
  const int h0 = (tile >> 4) * 8, w0 = (tile & 15) * 8;
  const int cg = t % 24, tw = t / 24;
  const int c = sel * 192 + cg * 8;

  float wgt[9][8];
#pragma unroll
  for (int tap = 0; tap < 9; ++tap) {
    float4 a = *(const float4*)&dwW[(size_t)tap * C3 + c];
    float4 b = *(const float4*)&dwW[(size_t)tap * C3 + c + 4];
    wgt[tap][0] = a.x; wgt[tap][1] = a.y; wgt[tap][2] = a.z; wgt[tap][3] = a.w;
    wgt[tap][4] = b.x; wgt[tap][5] = b.y; wgt[tap][6] = b.z; wgt[tap][7] = b.w;
  }

  const u16* src = pre + (size_t)brel * HWP * C3;
#pragma unroll
  for (int r = 0; r < 13; ++r) {
    int slot = t + r * 192;
    if (slot < 2400) {
      int pix = r * 8 + tw;
      int py = pix / 10, px = pix % 10;
      int gh = h0 - 1 + py, gw = w0 - 1 + px;
      uint4 v = make_uint4(0, 0, 0, 0);
      if ((unsigned)gh < 128u && (unsigned)gw < 128u)
        v = *(const uint4*)&src[(size_t)((gh << 7) + gw) * C3 + c];
      *(uint4*)&lds[slot * 8] = v;
    }
  }
  __syncthreads();

  float ssum[8] = {};
  u16* dstb = (sel == 0 ? qb : sel == 1 ? kb : vb) + (size_t)brel * PBF;
#pragma unroll
  for (int r = 0; r < 8; ++r) {
    float acc[8] = {};
#pragma unroll
    for (int dy = 0; dy < 3; ++dy)
#pragma unroll
      for (int dx = 0; dx < 3; ++dx) {
        uint4 v = *(const uint4*)&lds[(((r + dy) * 10 + tw + dx) * 24 + cg) * 8];
        const float* wg = wgt[dy * 3 + dx];
        acc[0] += bflo(v.x) * wg[0]; acc[1] += bfhi(v.x) * wg[1];
        acc[2] += bflo(v.y) * wg[2]; acc[3] += bfhi(v.y) * wg[3];
        acc[4] += bflo(v.z) * wg[4]; acc[5] += bfhi(v.z) * wg[5];
        acc[6] += bflo(v.w) * wg[6]; acc[7] += bfhi(v.w) * wg[7];
      }
    uint4 o;
    o.x = pk2(acc[0], acc[1]); o.y = pk2(acc[2], acc[3]);
    o.z = pk2(acc[4], acc[5]); o.w = pk2(acc[6], acc[7]);
    *(uint4*)&dstb[(size_t)(((h0 + r) << 7) + w0 + tw) * CIN + cg * 8] = o;
    if (sel < 2) {
#pragma unroll
      for (int i = 0; i < 8; ++i) ssum[i] += acc[i] * acc[i];
    }
  }

  if (sel < 2) {
    __syncthreads();
    float* fl = (float*)lds;
#pragma unroll
    for (int i = 0; i < 8; ++i) fl[tw * 192 + cg * 8 + i] = ssum[i];
    __syncthreads();
    float s = 0.f;
#pragma unroll
    for (int tw2 = 0; tw2 < 8; ++tw2) s += fl[tw2 * 192 + t];
    psum[(((size_t)sel * 8 + (b0 + brel)) * 192 + t) * 256 + tile] = s;
  }
}

// ---------------- reduce psum tiles -> rsqrt norms ----------------
__global__ __launch_bounds__(192) void rownorm2_k(
    const float* __restrict__ psum, float* __restrict__ rq, float* __restrict__ rk,
    int b0) {
  int sel = blockIdx.x, brel = blockIdx.y;
  int b = b0 + brel;
  int t = threadIdx.x;
  const float* p = psum + (((size_t)sel * 8 + b) * 192 + t) * 256;
  float s = 0.f;
#pragma unroll 4
  for (int i = 0; i < 256; i += 4) {
    float4 v = *(const float4*)&p[i];
    s += v.x + v.y + v.z + v.w;
  }
  (sel ? rk : rq)[b * CIN + t] = rsqrtf(fmaxf(s, 1e-12f));
}

// ---------------- QK^T via MFMA: per (sc,n,brel) 1-wave block, 48x48 over 512 s ----
// Q,K row-major [48][16384] bf16; operands loaded directly from global.
// Fragment layouts identical to gemm1 (A row = lane&15, k-group = lane>>4).
__global__ __launch_bounds__(64) void qk_mfma_k(
    const u16* __restrict__ qbuf, const u16* __restrict__ kbuf,
    float* __restrict__ partial, int b0) {
  int sc = blockIdx.x, n = blockIdx.y, brel = blockIdx.z;
  int b = b0 + brel;
  const int lane = threadIdx.x;
  const u16* qp = qbuf + (size_t)brel * PBF + (size_t)n * CH * HWP;
  const u16* kp = kbuf + (size_t)brel * PBF + (size_t)n * CH * HWP;
  const int lrow = lane & 15;
  const int lko = (lane >> 4) * 8;
  f32x4 acc[3][3];
#pragma unroll
  for (int mi = 0; mi < 3; ++mi)
#pragma unroll
    for (int nj = 0; nj < 3; ++nj) acc[mi][nj] = (f32x4){0.f, 0.f, 0.f, 0.f};

  const int sBeg = sc * 512;
#pragma unroll 4
  for (int kk = 0; kk < 16; ++kk) {
    const int s0 = sBeg + kk * 32 + lko;
    bf16x8 a[3], bb[3];
#pragma unroll
    for (int mi = 0; mi < 3; ++mi)
      a[mi] = *(const bf16x8*)&qp[(size_t)(mi * 16 + lrow) * HWP + s0];
#pragma unroll
    for (int nj = 0; nj < 3; ++nj)
      bb[nj] = *(const bf16x8*)&kp[(size_t)(nj * 16 + lrow) * HWP + s0];
#pragma unroll
    for (int mi = 0; mi < 3; ++mi)
#pragma unroll
      for (int nj = 0; nj < 3; ++nj)
        acc[mi][nj] = __builtin_amdgcn_mfma_f32_16x16x32_bf16(a[mi], bb[nj], acc[mi][nj], 0, 0, 0);
  }

  const int crow = (lane >> 4) * 4, ccol = lane & 15;
  float* pout = partial + (((size_t)b * NHD + n) * NS + sc) * CH * CH;
#pragma unroll
  for (int mi = 0; mi < 3; ++mi)
#pragma unroll
    for (int nj = 0; nj < 3; ++nj)
#pragma unroll
      for (int rr = 0; rr < 4; ++rr)
        pout[(size_t)(mi * 16 + crow + rr) * CH + nj * 16 + ccol] = acc[mi][nj][rr];
}

// ---------------- reduce partials, scale, softmax over j ----------------
__global__ __launch_bounds__(64) void softmax_k(
    const float* __restrict__ partial, const float* __restrict__ rq, const float* __restrict__ rk,
    const float* __restrict__ temp, float* __restrict__ attn, int b0) {
  int i = blockIdx.x % CH;
  int n = (blockIdx.x / CH) % NHD;
  int brel = blockIdx.x / (CH * NHD);
  int b = b0 + brel;
  int j = threadIdx.x;
  float logit = -INFINITY;
  if (j < CH) {
    float s = 0.f;
#pragma unroll 8
    for (int sc = 0; sc < NS; ++sc)
      s += partial[((((size_t)b * NHD + n) * NS + sc) * CH + i) * CH + j];
    logit = s * rq[b * CIN + n * CH + i] * rk[b * CIN + n * CH + j] * temp[n];
  }
  float m = logit;
#pragma unroll
  for (int o = 32; o > 0; o >>= 1) m = fmaxf(m, __shfl_xor(m, o));
  float e = (j < CH) ? expf(logit - m) : 0.f;
  float sum = e;
#pragma unroll
  for (int o = 32; o > 0; o >>= 1) sum += __shfl_xor(sum, o);
  if (j < CH) attn[(((size_t)b * NHD + n) * CH + i) * CH + j] = e / sum;
}

// ---------------- O = attn * V (bf16 V in, bf16 O out) ----------------
__global__ __launch_bounds__(256) void av_k(
    const float* __restrict__ attn, const u16* __restrict__ vbuf,
    u16* __restrict__ obuf, int b0) {
  int st = blockIdx.x, n = blockIdx.y, brel = blockIdx.z;
  int b = b0 + brel;
  __shared__ float as_[CH * CH];
  int t = threadIdx.x;
  const float* ap = attn + ((size_t)b * NHD + n) * CH * CH;
#pragma unroll
  for (int r = 0; r < 9; ++r) as_[t + r * 256] = ap[t + r * 256];
  __syncthreads();
  int s = st * 512 + t * 2;
  const u16* vp = vbuf + (size_t)brel * PBF + (size_t)n * CH * HWP;
  float2 acc[CH];
#pragma unroll
  for (int d = 0; d < CH; ++d) { acc[d].x = 0.f; acc[d].y = 0.f; }
#pragma unroll 4
  for (int j4 = 0; j4 < 12; ++j4) {
    unsigned int u0 = *(const unsigned int*)&vp[(size_t)(j4 * 4 + 0) * HWP + s];
    unsigned int u1 = *(const unsigned int*)&vp[(size_t)(j4 * 4 + 1) * HWP + s];
    unsigned int u2 = *(const unsigned int*)&vp[(size_t)(j4 * 4 + 2) * HWP + s];
    unsigned int u3 = *(const unsigned int*)&vp[(size_t)(j4 * 4 + 3) * HWP + s];
    float2 v0 = make_float2(bflo(u0), bfhi(u0));
    float2 v1 = make_float2(bflo(u1), bfhi(u1));
    float2 v2 = make_float2(bflo(u2), bfhi(u2));
    float2 v3 = make_float2(bflo(u3), bfhi(u3));
#pragma unroll
    for (int d = 0; d < CH; ++d) {
      float4 a4 = *(const float4*)&as_[d * CH + j4 * 4];
      acc[d].x += a4.x * v0.x + a4.y * v1.x + a4.z * v2.x + a4.w * v3.x;
      acc[d].y += a4.x * v0.y + a4.y * v1.y + a4.z * v2.y + a4.w * v3.y;
    }
  }
  u16* op = obuf + (size_t)brel * PBF + (size_t)n * CH * HWP;
#pragma unroll
  for (int d = 0; d < CH; ++d) {
    ushort2 o; o.x = f2bf(acc[d].x); o.y = f2bf(acc[d].y);
    *(ushort2*)&op[(size_t)d * HWP + s] = o;
  }
}

extern "C" void kernel_launch(void* const* d_in, const int* in_sizes, int n_in,
                              void* d_out, int out_size, void* d_ws, size_t ws_size,
                              hipStream_t stream) {
  const float* x      = (const float*)d_in[0];
  const float* qkv_w  = (const float*)d_in[1];
  const float* dw_w   = (const float*)d_in[2];
  const float* proj_w = (const float*)d_in[3];
  const float* temp   = (const float*)d_in[4];
  float* out = (float*)d_out;

  // fixed buffers
  float* rq      = (float*)d_ws;                        // 8*192
  float* rk      = rq + 8 * CIN;                        // 8*192
  float* attn    = rk + 8 * CIN;                        // 8*4*48*48
  float* partial = attn + 8 * NHD * CH * CH;            // 8*4*NS*48*48
  float* psum    = partial + (size_t)8 * NHD * NS * CH * CH;  // 2*8*192*256
  u16* qkvwT  = (u16*)(psum + (size_t)2 * 8 * 192 * 256);
  u16* projwT = qkvwT + (size_t)C3 * CIN;
  char* bufbase = (char*)(projwT + (size_t)CIN * CIN);
  size_t off = (size_t)(bufbase - (char*)d_ws);
  off = (off + 255) & ~(size_t)255;

  // per-batch: qkv_pre bf16 + q,k,v,o bf16
  const size_t perBatchBytes = (size_t)HWP * C3 * 2 + 4 * (size_t)PBF * 2;
  size_t avail = ws_size > off ? ws_size - off : 0;
  int nb = (int)(avail / perBatchBytes);
  if (nb < 1) nb = 1;
  if (nb > 8) nb = 8;

  u16* qkv_pre = (u16*)((char*)d_ws + off);
  u16* qbuf = qkv_pre + (size_t)nb * HWP * C3;
  u16* kbuf = qbuf + (size_t)nb * PBF;
  u16* vbuf = kbuf + (size_t)nb * PBF;
  u16* obuf = vbuf + (size_t)nb * PBF;

  convert_w_k<<<dim3((C3 * CIN + CIN * CIN + 255) / 256), 256, 0, stream>>>(
      qkv_w, proj_w, qkvwT, projwT);

  for (int b0 = 0; b0 < 8; b0 += nb) {
    int nbc = (8 - b0) < nb ? (8 - b0) : nb;
    int M = nbc * HWP;
    // 1) qkv = x @ qkv_w  (fp32 A fused-convert, bf16 C)
    gemm1<true, true><<<dim3((M / 128) * (C3 / 64)), 256, 0, stream>>>(
        x + (size_t)b0 * HWP * CIN, qkvwT, qkv_pre, C3);
    // 2) depthwise 3x3 (LDS-staged) + split q/k/v + fused q/k sq-sum partials
    dwconv_k<<<dim3(256, 3, nbc), 192, 0, stream>>>(
        qkv_pre, dw_w, qbuf, kbuf, vbuf, psum, b0);
    // 3) reduce partials -> rsqrt norms
    rownorm2_k<<<dim3(2, nbc), 192, 0, stream>>>(psum, rq, rk, b0);
    // 4) QK^T partials via MFMA
    qk_mfma_k<<<dim3(NS, NHD, nbc), 64, 0, stream>>>(qbuf, kbuf, partial, b0);
    // 5) reduce + scale + softmax
    softmax_k<<<dim3(nbc * NHD * CH), 64, 0, stream>>>(partial, rq, rk, temp, attn, b0);
    // 6) O = attn @ V
    av_k<<<dim3(HWP / 512, NHD, nbc), 256, 0, stream>>>(attn, vbuf, obuf, b0);
    // 7) out = O @ proj_w  (bf16 A, fp32 C)
    gemm1<false, false><<<dim3((M / 128) * (CIN / 64)), 256, 0, stream>>>(
        obuf, projwT, out + (size_t)b0 * HWP * CIN, CIN);
  }
}